// Round 1
// baseline (756.177 us; speedup 1.0000x reference)
//
#include <hip/hip_runtime.h>

#define B_    2
#define S_    2048
#define HID_  2048
#define NH_   16
#define NKV_  2
#define HD_   128
#define M_    (B_*S_)     // 4096
#define NQKV_ 2560
#define KD_   2048

typedef unsigned short u16;
typedef unsigned int   u32;
typedef __bf16 bf16x8 __attribute__((ext_vector_type(8)));
typedef float  f32x4  __attribute__((ext_vector_type(4)));

__device__ __forceinline__ u16 f2b(float x){
  u32 u = __builtin_bit_cast(u32, x);
  return (u16)((u + 0x7FFFu + ((u>>16)&1u)) >> 16);
}
__device__ __forceinline__ u32 pack2bf(float lo, float hi){
  u32 a = __builtin_bit_cast(u32, lo), b = __builtin_bit_cast(u32, hi);
  a = (a + 0x7FFFu + ((a>>16)&1u)) >> 16;
  b = (b + 0x7FFFu + ((b>>16)&1u)) >> 16;
  return a | (b<<16);
}

// ---------------- convert f32 -> bf16 (hidden, Wqkv concat, Wo) ----------------
__global__ void convert_kernel(const float* __restrict__ hid, const float* __restrict__ Wq,
                               const float* __restrict__ Wk, const float* __restrict__ Wv,
                               const float* __restrict__ Wo, u16* __restrict__ hid_b,
                               u16* __restrict__ wqkv_b, u16* __restrict__ wo_b) {
  long e = ((long)blockIdx.x*256 + threadIdx.x) * 4;
  const float* src; u16* dst; long off;
  if      (e <  8388608) { src = hid; dst = hid_b;            off = e; }
  else if (e < 12582912) { src = Wq;  dst = wqkv_b;           off = e -  8388608; }
  else if (e < 13107200) { src = Wk;  dst = wqkv_b + 4194304; off = e - 12582912; }
  else if (e < 13631488) { src = Wv;  dst = wqkv_b + 4718592; off = e - 13107200; }
  else                   { src = Wo;  dst = wo_b;             off = e - 13631488; }
  float4 v = *(const float4*)(src + off);
  u16 r0 = f2b(v.x), r1 = f2b(v.y), r2 = f2b(v.z), r3 = f2b(v.w);
  u32 lo = (u32)r0 | ((u32)r1<<16), hi2 = (u32)r2 | ((u32)r3<<16);
  *(uint2*)(dst + off) = make_uint2(lo, hi2);
}

// ---------------- RoPE tables [S][64] ----------------
__global__ void rope_kernel(float* __restrict__ cosT, float* __restrict__ sinT) {
  int idx = blockIdx.x*256 + threadIdx.x;   // S_*64
  int s = idx >> 6, d = idx & 63;
  float inv = powf(1000000.0f, -(float)d * (1.0f/64.0f));
  float ang = (float)s * inv;
  cosT[idx] = cosf(ang);
  sinT[idx] = sinf(ang);
}

// ---------------- bf16 B^T GEMM: C[m][n] = sum_k A[m][k]*Bw[n][k] ----------------
// tile 128x128, BK=32, 256 threads (4 waves 2x2), reg-staged LDS
__global__ __launch_bounds__(256) void gemm_bt(const u16* __restrict__ A, const u16* __restrict__ Bw,
                                               float* __restrict__ C, int Ndim, int Kdim) {
  __shared__ __align__(16) u16 As[128*32];
  __shared__ __align__(16) u16 Bs[128*32];
  int m0 = blockIdx.x*128, n0 = blockIdx.y*128;
  int tid = threadIdx.x, lane = tid & 63, w = tid >> 6;
  int wm = w & 1, wn = w >> 1;
  int r = lane & 15, g = lane >> 4;
  f32x4 acc[4][4] = {};
  for (int k0 = 0; k0 < Kdim; k0 += 32) {
    uint4 va[2], vb[2];
    #pragma unroll
    for (int j = 0; j < 2; ++j) {
      int flatb = (j*256 + tid) * 16;           // byte offset in 8KB tile
      int row = flatb >> 6, colb = flatb & 63;  // row 0..127, col element colb/2
      va[j] = *(const uint4*)(A  + (long)(m0+row)*Kdim + k0 + (colb>>1));
      vb[j] = *(const uint4*)(Bw + (long)(n0+row)*Kdim + k0 + (colb>>1));
    }
    __syncthreads();
    #pragma unroll
    for (int j = 0; j < 2; ++j) {
      int flatb = (j*256 + tid) * 16;
      *(uint4*)((char*)As + flatb) = va[j];
      *(uint4*)((char*)Bs + flatb) = vb[j];
    }
    __syncthreads();
    bf16x8 af[4], bf[4];
    #pragma unroll
    for (int mf = 0; mf < 4; ++mf) af[mf] = *(const bf16x8*)(As + (wm*64 + mf*16 + r)*32 + g*8);
    #pragma unroll
    for (int nf = 0; nf < 4; ++nf) bf[nf] = *(const bf16x8*)(Bs + (wn*64 + nf*16 + r)*32 + g*8);
    #pragma unroll
    for (int mf = 0; mf < 4; ++mf)
      #pragma unroll
      for (int nf = 0; nf < 4; ++nf)
        acc[mf][nf] = __builtin_amdgcn_mfma_f32_16x16x32_bf16(af[mf], bf[nf], acc[mf][nf], 0, 0, 0);
  }
  #pragma unroll
  for (int mf = 0; mf < 4; ++mf)
    #pragma unroll
    for (int nf = 0; nf < 4; ++nf)
      #pragma unroll
      for (int i = 0; i < 4; ++i) {
        int row = m0 + wm*64 + mf*16 + g*4 + i;
        int col = n0 + wn*64 + nf*16 + r;
        C[(long)row*Ndim + col] = acc[mf][nf][i];
      }
}

// ---------------- QKV epilogue: bias + RoPE + layout ----------------
__global__ void qkv_epilogue(const float* __restrict__ C, const float* __restrict__ bq,
                             const float* __restrict__ bk, const float* __restrict__ bv,
                             const float* __restrict__ cosT, const float* __restrict__ sinT,
                             u16* __restrict__ Qb, u16* __restrict__ Kb, u16* __restrict__ VTb) {
  int s = blockIdx.x, b = blockIdx.y, t = threadIdx.x;
  long m = (long)b*S_ + s;
  const float* Crow = C + m*NQKV_;
  const float* cr = cosT + s*64;
  const float* sr = sinT + s*64;
  // Q: 16 heads x 64 pairs = 1024 tasks
  #pragma unroll
  for (int it = 0; it < 4; ++it) {
    int task = t + it*256;
    int h = task >> 6, dp = task & 63;
    int c1 = h*128 + dp, c2 = c1 + 64;
    float x1 = Crow[c1] + bq[c1], x2 = Crow[c2] + bq[c2];
    float cc = cr[dp], ss = sr[dp];
    Qb[m*HID_ + c1] = f2b(x1*cc - x2*ss);
    Qb[m*HID_ + c2] = f2b(x2*cc + x1*ss);
  }
  // K: 2 heads x 64 pairs = 128 tasks
  if (t < 128) {
    int kvh = t >> 6, dp = t & 63;
    int c1 = kvh*128 + dp, c2 = c1 + 64;
    float x1 = Crow[2048 + c1] + bk[c1], x2 = Crow[2048 + c2] + bk[c2];
    float cc = cr[dp], ss = sr[dp];
    long base = ((long)(b*NKV_ + kvh)*S_ + s) * HD_;
    Kb[base + dp]      = f2b(x1*cc - x2*ss);
    Kb[base + dp + 64] = f2b(x2*cc + x1*ss);
  }
  // V: 256 tasks, store transposed [b][kvh][d][s]
  {
    int kvh = t >> 7, d = t & 127;
    float v = Crow[2304 + t] + bv[t];
    VTb[((long)(b*NKV_ + kvh)*HD_ + d)*S_ + s] = f2b(v);
  }
}

// ---------------- flash attention: BQ=64 (4 waves x 16 rows), BK=64 ----------------
__global__ __launch_bounds__(256) void attn_kernel(const u16* __restrict__ Qb, const u16* __restrict__ Kb,
                                                   const u16* __restrict__ VTb, u16* __restrict__ Ob) {
  __shared__ __align__(16) u16 Ks[64*128];   // [kv][d], XOR-swizzled
  __shared__ __align__(16) u16 Vs[128*64];   // [d][kv], XOR-swizzled
  int qt = (int)(gridDim.x - 1) - (int)blockIdx.x;   // heavy tiles first
  int h = blockIdx.y, b = blockIdx.z;
  int kvh = h >> 3;
  int tid = threadIdx.x, lane = tid & 63, w = tid >> 6;
  int q0 = qt*64 + w*16;
  int qr = lane & 15, g = lane >> 4;

  bf16x8 qf[4];
  const u16* qbase = Qb + ((long)(b*S_) + q0 + qr)*HID_ + h*HD_;
  #pragma unroll
  for (int kf = 0; kf < 4; ++kf) qf[kf] = *(const bf16x8*)(qbase + kf*32 + g*8);

  f32x4 acc[8] = {};
  float m_run = -3e38f, l_run = 0.f;

  const u16* Kg = Kb  + (long)(b*NKV_ + kvh)*S_*HD_;
  const u16* Vg = VTb + (long)(b*NKV_ + kvh)*HD_*S_;

  const float SCALE = 0.08838834764831845f;  // 1/sqrt(128)
  int nt = qt + 1;
  for (int t = 0; t < nt; ++t) {
    int kv0 = t*64;
    __syncthreads();
    #pragma unroll
    for (int j = 0; j < 4; ++j) {
      int c = j*256 + tid;
      { // K tile: 64 rows x 256B (16 chunks/row)
        int rr = c >> 4, cc = c & 15;
        uint4 kd = *(const uint4*)(Kg + (long)(kv0 + rr)*HD_ + cc*8);
        *(uint4*)(&Ks[rr*128 + ((cc*8) ^ ((rr&7)<<3))]) = kd;
      }
      { // VT tile: 128 rows x 128B (8 chunks/row)
        int dd = c >> 3, cc = c & 7;
        uint4 vd = *(const uint4*)(Vg + (long)dd*S_ + kv0 + cc*8);
        *(uint4*)(&Vs[dd*64 + ((cc*8) ^ ((dd&7)<<3))]) = vd;
      }
    }
    __syncthreads();

    // swapped QK^T: D[kv,q] per 16-kv strip; lane holds q=qr, kv = mf*16+g*4+i
    float p[4][4];
    #pragma unroll
    for (int mf = 0; mf < 4; ++mf) {
      f32x4 sacc = {};
      #pragma unroll
      for (int kf = 0; kf < 4; ++kf) {
        int kr = mf*16 + qr;
        bf16x8 kfr = *(const bf16x8*)(&Ks[kr*128 + ((g*8 + kf*32) ^ ((kr&7)<<3))]);
        sacc = __builtin_amdgcn_mfma_f32_16x16x32_bf16(kfr, qf[kf], sacc, 0, 0, 0);
      }
      #pragma unroll
      for (int i = 0; i < 4; ++i) p[mf][i] = sacc[i];
    }

    bool diag = (t == qt);
    float tmax = -3e38f;
    #pragma unroll
    for (int mf = 0; mf < 4; ++mf)
      #pragma unroll
      for (int i = 0; i < 4; ++i) {
        float sv = p[mf][i] * SCALE;
        if (diag) {
          int kvg = kv0 + mf*16 + g*4 + i;
          if (kvg > q0 + qr) sv = -1e9f;
        }
        p[mf][i] = sv;
        tmax = fmaxf(tmax, sv);
      }
    tmax = fmaxf(tmax, __shfl_xor(tmax, 16));
    tmax = fmaxf(tmax, __shfl_xor(tmax, 32));
    float m_new = fmaxf(m_run, tmax);
    float sf = __expf(m_run - m_new);
    float psum = 0.f;
    #pragma unroll
    for (int mf = 0; mf < 4; ++mf)
      #pragma unroll
      for (int i = 0; i < 4; ++i) {
        float ev = __expf(p[mf][i] - m_new);
        p[mf][i] = ev;
        psum += ev;
      }
    psum += __shfl_xor(psum, 16);
    psum += __shfl_xor(psum, 32);
    l_run = l_run * sf + psum;
    m_run = m_new;
    // rescale O accumulators (their q index is g*4+i, sf lives at lane q)
    #pragma unroll
    for (int i = 0; i < 4; ++i) {
      float sfi = __shfl(sf, (g<<2) + i);
      #pragma unroll
      for (int nf = 0; nf < 8; ++nf) acc[nf][i] *= sfi;
    }

    // pack P to bf16 pairs and redistribute to A-fragment layout (q=lane&15, kv contiguous)
    u32 pk[4][2];
    #pragma unroll
    for (int mf = 0; mf < 4; ++mf) {
      pk[mf][0] = pack2bf(p[mf][0], p[mf][1]);
      pk[mf][1] = pack2bf(p[mf][2], p[mf][3]);
    }
    int srcA = qr + 32*(g & 1);
    int srcB = srcA + 16;
    bool hi = (g >> 1) & 1;
    #pragma unroll
    for (int ks = 0; ks < 2; ++ks) {
      u32 a0 = (u32)__shfl((int)pk[2*ks  ][0], srcA), a1 = (u32)__shfl((int)pk[2*ks  ][1], srcA);
      u32 b0 = (u32)__shfl((int)pk[2*ks+1][0], srcA), b1 = (u32)__shfl((int)pk[2*ks+1][1], srcA);
      u32 c0 = (u32)__shfl((int)pk[2*ks  ][0], srcB), c1 = (u32)__shfl((int)pk[2*ks  ][1], srcB);
      u32 d0 = (u32)__shfl((int)pk[2*ks+1][0], srcB), d1 = (u32)__shfl((int)pk[2*ks+1][1], srcB);
      uint4 pw;
      pw.x = hi ? b0 : a0;  pw.y = hi ? b1 : a1;
      pw.z = hi ? d0 : c0;  pw.w = hi ? d1 : c1;
      bf16x8 pa = __builtin_bit_cast(bf16x8, pw);
      #pragma unroll
      for (int nf = 0; nf < 8; ++nf) {
        int vr = nf*16 + qr;
        bf16x8 vf = *(const bf16x8*)(&Vs[vr*64 + ((g*8 + ks*32) ^ ((vr&7)<<3))]);
        acc[nf] = __builtin_amdgcn_mfma_f32_16x16x32_bf16(pa, vf, acc[nf], 0, 0, 0);
      }
    }
  }

  float linv[4];
  #pragma unroll
  for (int i = 0; i < 4; ++i) {
    float li = __shfl(l_run, (g<<2) + i);
    linv[i] = 1.0f / li;
  }
  #pragma unroll
  for (int nf = 0; nf < 8; ++nf)
    #pragma unroll
    for (int i = 0; i < 4; ++i) {
      int qrow = q0 + g*4 + i;
      Ob[((long)(b*S_ + qrow))*HID_ + h*HD_ + nf*16 + qr] = f2b(acc[nf][i] * linv[i]);
    }
}

extern "C" void kernel_launch(void* const* d_in, const int* in_sizes, int n_in,
                              void* d_out, int out_size, void* d_ws, size_t ws_size,
                              hipStream_t stream) {
  const float* hid = (const float*)d_in[0];
  const float* Wq  = (const float*)d_in[3];
  const float* bq  = (const float*)d_in[4];
  const float* Wk  = (const float*)d_in[5];
  const float* bk  = (const float*)d_in[6];
  const float* Wv  = (const float*)d_in[7];
  const float* bv  = (const float*)d_in[8];
  const float* Wo  = (const float*)d_in[9];
  char* ws = (char*)d_ws;
  float* cosT  = (float*)(ws + 0);
  float* sinT  = (float*)(ws + 524288);
  u16* hid_b   = (u16*)(ws + 1048576);
  u16* wqkv_b  = (u16*)(ws + 17825792);
  u16* wo_b    = (u16*)(ws + 28311552);
  float* Cqkv  = (float*)(ws + 36700160);
  u16* Qb      = (u16*)(ws + 78643200);
  u16* Kb      = (u16*)(ws + 95420416);
  u16* VTb     = (u16*)(ws + 97517568);
  u16* Ob      = (u16*)(ws + 99614720);

  hipLaunchKernelGGL(convert_kernel, dim3(17408), dim3(256), 0, stream,
                     hid, Wq, Wk, Wv, Wo, hid_b, wqkv_b, wo_b);
  hipLaunchKernelGGL(rope_kernel, dim3(512), dim3(256), 0, stream, cosT, sinT);
  hipLaunchKernelGGL(gemm_bt, dim3(32, 20), dim3(256), 0, stream,
                     hid_b, wqkv_b, Cqkv, NQKV_, KD_);
  hipLaunchKernelGGL(qkv_epilogue, dim3(2048, 2), dim3(256), 0, stream,
                     Cqkv, bq, bk, bv, cosT, sinT, Qb, Kb, VTb);
  hipLaunchKernelGGL(attn_kernel, dim3(32, 16, 2), dim3(256), 0, stream,
                     Qb, Kb, VTb, Ob);
  hipLaunchKernelGGL(gemm_bt, dim3(32, 16), dim3(256), 0, stream,
                     Ob, wo_b, (float*)d_out, HID_, KD_);
}

// Round 2
// 505.576 us; speedup vs baseline: 1.4957x; 1.4957x over previous
//
#include <hip/hip_runtime.h>

#define B_    2
#define S_    2048
#define HID_  2048
#define NH_   16
#define NKV_  2
#define HD_   128
#define M_    (B_*S_)     // 4096
#define NQKV_ 2560
#define KD_   2048

typedef unsigned short u16;
typedef unsigned int   u32;
typedef __bf16 bf16x8 __attribute__((ext_vector_type(8)));
typedef float  f32x4  __attribute__((ext_vector_type(4)));

#define GLOAD_LDS16(gp, lp) \
  __builtin_amdgcn_global_load_lds((const __attribute__((address_space(1))) unsigned int*)(gp), \
                                   (__attribute__((address_space(3))) unsigned int*)(lp), 16, 0, 0)

__device__ __forceinline__ u16 f2b(float x){
  u32 u = __builtin_bit_cast(u32, x);
  return (u16)((u + 0x7FFFu + ((u>>16)&1u)) >> 16);
}
__device__ __forceinline__ u32 pack2bf(float lo, float hi){
  u32 a = __builtin_bit_cast(u32, lo), b = __builtin_bit_cast(u32, hi);
  a = (a + 0x7FFFu + ((a>>16)&1u)) >> 16;
  b = (b + 0x7FFFu + ((b>>16)&1u)) >> 16;
  return a | (b<<16);
}

// ---------------- convert f32 -> bf16 (hidden, Wqkv concat, Wo) ----------------
__global__ void convert_kernel(const float* __restrict__ hid, const float* __restrict__ Wq,
                               const float* __restrict__ Wk, const float* __restrict__ Wv,
                               const float* __restrict__ Wo, u16* __restrict__ hid_b,
                               u16* __restrict__ wqkv_b, u16* __restrict__ wo_b) {
  long e = ((long)blockIdx.x*256 + threadIdx.x) * 4;
  const float* src; u16* dst; long off;
  if      (e <  8388608) { src = hid; dst = hid_b;            off = e; }
  else if (e < 12582912) { src = Wq;  dst = wqkv_b;           off = e -  8388608; }
  else if (e < 13107200) { src = Wk;  dst = wqkv_b + 4194304; off = e - 12582912; }
  else if (e < 13631488) { src = Wv;  dst = wqkv_b + 4718592; off = e - 13107200; }
  else                   { src = Wo;  dst = wo_b;             off = e - 13631488; }
  float4 v = *(const float4*)(src + off);
  u16 r0 = f2b(v.x), r1 = f2b(v.y), r2 = f2b(v.z), r3 = f2b(v.w);
  u32 lo = (u32)r0 | ((u32)r1<<16), hi2 = (u32)r2 | ((u32)r3<<16);
  *(uint2*)(dst + off) = make_uint2(lo, hi2);
}

// ---------------- RoPE tables [S][64] ----------------
__global__ void rope_kernel(float* __restrict__ cosT, float* __restrict__ sinT) {
  int idx = blockIdx.x*256 + threadIdx.x;   // S_*64
  int s = idx >> 6, d = idx & 63;
  float inv = powf(1000000.0f, -(float)d * (1.0f/64.0f));
  float ang = (float)s * inv;
  cosT[idx] = cosf(ang);
  sinT[idx] = sinf(ang);
}

// ---------------- bf16 B^T GEMM: C[m][n] = sum_k A[m][k]*Bw[n][k] ----------------
// m97 structure: tile 128x128, BK=32, 256 threads (4 waves 2x2),
// global_load_lds width=16 staging, linear LDS, 2 barriers per K-step.
__global__ __launch_bounds__(256) void gemm_bt(const u16* __restrict__ A, const u16* __restrict__ Bw,
                                               float* __restrict__ C, int Ndim, int Kdim) {
  __shared__ __align__(16) u16 As[128*32];
  __shared__ __align__(16) u16 Bs[128*32];
  int m0 = blockIdx.x*128, n0 = blockIdx.y*128;
  int tid = threadIdx.x, lane = tid & 63, w = tid >> 6;
  int wm = w & 1, wn = w >> 1;
  int r = lane & 15, g = lane >> 4;
  f32x4 acc[4][4] = {};

  // staging geometry: wave w owns tile bytes [w*2048, w*2048+2048) in two
  // 1KB instructions; lane l's 16B lands at w*2048 + j*1024 + l*16
  //   -> row = w*32 + j*16 + (l>>2), col_u16 = (l&3)*8
  const u16* aGP = A  + (long)(m0 + w*32 + (lane>>2))*Kdim + (lane&3)*8;
  const u16* bGP = Bw + (long)(n0 + w*32 + (lane>>2))*Kdim + (lane&3)*8;
  u16* aLP = As + w*1024;         // wave-uniform LDS base (u16 units; 2048B per wave)
  u16* bLP = Bs + w*1024;
  const long rowskip = (long)16*Kdim;

  for (int k0 = 0; k0 < Kdim; k0 += 32) {
    GLOAD_LDS16(aGP + k0,           aLP);
    GLOAD_LDS16(aGP + k0 + rowskip, aLP + 512);
    GLOAD_LDS16(bGP + k0,           bLP);
    GLOAD_LDS16(bGP + k0 + rowskip, bLP + 512);
    __syncthreads();
    bf16x8 af[4], bf[4];
    #pragma unroll
    for (int mf = 0; mf < 4; ++mf) af[mf] = *(const bf16x8*)(As + (wm*64 + mf*16 + r)*32 + g*8);
    #pragma unroll
    for (int nf = 0; nf < 4; ++nf) bf[nf] = *(const bf16x8*)(Bs + (wn*64 + nf*16 + r)*32 + g*8);
    #pragma unroll
    for (int mf = 0; mf < 4; ++mf)
      #pragma unroll
      for (int nf = 0; nf < 4; ++nf)
        acc[mf][nf] = __builtin_amdgcn_mfma_f32_16x16x32_bf16(af[mf], bf[nf], acc[mf][nf], 0, 0, 0);
    __syncthreads();
  }
  #pragma unroll
  for (int mf = 0; mf < 4; ++mf)
    #pragma unroll
    for (int nf = 0; nf < 4; ++nf)
      #pragma unroll
      for (int i = 0; i < 4; ++i) {
        int row = m0 + wm*64 + mf*16 + g*4 + i;
        int col = n0 + wn*64 + nf*16 + r;
        C[(long)row*Ndim + col] = acc[mf][nf][i];
      }
}

// ---------------- QKV epilogue: bias + RoPE + layout ----------------
__global__ void qkv_epilogue(const float* __restrict__ C, const float* __restrict__ bq,
                             const float* __restrict__ bk, const float* __restrict__ bv,
                             const float* __restrict__ cosT, const float* __restrict__ sinT,
                             u16* __restrict__ Qb, u16* __restrict__ Kb, u16* __restrict__ VTb) {
  int s = blockIdx.x, b = blockIdx.y, t = threadIdx.x;
  long m = (long)b*S_ + s;
  const float* Crow = C + m*NQKV_;
  const float* cr = cosT + s*64;
  const float* sr = sinT + s*64;
  // Q: 16 heads x 64 pairs = 1024 tasks
  #pragma unroll
  for (int it = 0; it < 4; ++it) {
    int task = t + it*256;
    int h = task >> 6, dp = task & 63;
    int c1 = h*128 + dp, c2 = c1 + 64;
    float x1 = Crow[c1] + bq[c1], x2 = Crow[c2] + bq[c2];
    float cc = cr[dp], ss = sr[dp];
    Qb[m*HID_ + c1] = f2b(x1*cc - x2*ss);
    Qb[m*HID_ + c2] = f2b(x2*cc + x1*ss);
  }
  // K: 2 heads x 64 pairs = 128 tasks
  if (t < 128) {
    int kvh = t >> 6, dp = t & 63;
    int c1 = kvh*128 + dp, c2 = c1 + 64;
    float x1 = Crow[2048 + c1] + bk[c1], x2 = Crow[2048 + c2] + bk[c2];
    float cc = cr[dp], ss = sr[dp];
    long base = ((long)(b*NKV_ + kvh)*S_ + s) * HD_;
    Kb[base + dp]      = f2b(x1*cc - x2*ss);
    Kb[base + dp + 64] = f2b(x2*cc + x1*ss);
  }
  // V: 256 tasks, store transposed [b][kvh][d][s]
  {
    int kvh = t >> 7, d = t & 127;
    float v = Crow[2304 + t] + bv[t];
    VTb[((long)(b*NKV_ + kvh)*HD_ + d)*S_ + s] = f2b(v);
  }
}

// ---------------- flash attention: BQ=64 (4 waves x 16 rows), BK=64 ----------------
__global__ __launch_bounds__(256) void attn_kernel(const u16* __restrict__ Qb, const u16* __restrict__ Kb,
                                                   const u16* __restrict__ VTb, u16* __restrict__ Ob) {
  __shared__ __align__(16) u16 Ks[64*128];   // [kv][d], XOR-swizzled
  __shared__ __align__(16) u16 Vs[128*64];   // [d][kv], XOR-swizzled
  int qt = (int)(gridDim.x - 1) - (int)blockIdx.x;   // heavy tiles first
  int h = blockIdx.y, b = blockIdx.z;
  int kvh = h >> 3;
  int tid = threadIdx.x, lane = tid & 63, w = tid >> 6;
  int q0 = qt*64 + w*16;
  int qr = lane & 15, g = lane >> 4;

  bf16x8 qf[4];
  const u16* qbase = Qb + ((long)(b*S_) + q0 + qr)*HID_ + h*HD_;
  #pragma unroll
  for (int kf = 0; kf < 4; ++kf) qf[kf] = *(const bf16x8*)(qbase + kf*32 + g*8);

  f32x4 acc[8] = {};
  float m_run = -3e38f, l_run = 0.f;

  const u16* Kg = Kb  + (long)(b*NKV_ + kvh)*S_*HD_;
  const u16* Vg = VTb + (long)(b*NKV_ + kvh)*HD_*S_;

  const float SCALE = 0.08838834764831845f;  // 1/sqrt(128)
  int nt = qt + 1;
  for (int t = 0; t < nt; ++t) {
    int kv0 = t*64;
    __syncthreads();
    #pragma unroll
    for (int j = 0; j < 4; ++j) {
      int c = j*256 + tid;
      { // K tile: 64 rows x 256B (16 chunks/row)
        int rr = c >> 4, cc = c & 15;
        uint4 kd = *(const uint4*)(Kg + (long)(kv0 + rr)*HD_ + cc*8);
        *(uint4*)(&Ks[rr*128 + ((cc*8) ^ ((rr&7)<<3))]) = kd;
      }
      { // VT tile: 128 rows x 128B (8 chunks/row)
        int dd = c >> 3, cc = c & 7;
        uint4 vd = *(const uint4*)(Vg + (long)dd*S_ + kv0 + cc*8);
        *(uint4*)(&Vs[dd*64 + ((cc*8) ^ ((dd&7)<<3))]) = vd;
      }
    }
    __syncthreads();

    // swapped QK^T: D[kv,q] per 16-kv strip; lane holds q=qr, kv = mf*16+g*4+i
    float p[4][4];
    #pragma unroll
    for (int mf = 0; mf < 4; ++mf) {
      f32x4 sacc = {};
      #pragma unroll
      for (int kf = 0; kf < 4; ++kf) {
        int kr = mf*16 + qr;
        bf16x8 kfr = *(const bf16x8*)(&Ks[kr*128 + ((g*8 + kf*32) ^ ((kr&7)<<3))]);
        sacc = __builtin_amdgcn_mfma_f32_16x16x32_bf16(kfr, qf[kf], sacc, 0, 0, 0);
      }
      #pragma unroll
      for (int i = 0; i < 4; ++i) p[mf][i] = sacc[i];
    }

    bool diag = (t == qt);
    float tmax = -3e38f;
    #pragma unroll
    for (int mf = 0; mf < 4; ++mf)
      #pragma unroll
      for (int i = 0; i < 4; ++i) {
        float sv = p[mf][i] * SCALE;
        if (diag) {
          int kvg = kv0 + mf*16 + g*4 + i;
          if (kvg > q0 + qr) sv = -1e9f;
        }
        p[mf][i] = sv;
        tmax = fmaxf(tmax, sv);
      }
    tmax = fmaxf(tmax, __shfl_xor(tmax, 16));
    tmax = fmaxf(tmax, __shfl_xor(tmax, 32));
    float m_new = fmaxf(m_run, tmax);
    float sf = __expf(m_run - m_new);
    float psum = 0.f;
    #pragma unroll
    for (int mf = 0; mf < 4; ++mf)
      #pragma unroll
      for (int i = 0; i < 4; ++i) {
        float ev = __expf(p[mf][i] - m_new);
        p[mf][i] = ev;
        psum += ev;
      }
    psum += __shfl_xor(psum, 16);
    psum += __shfl_xor(psum, 32);
    l_run = l_run * sf + psum;
    m_run = m_new;
    // rescale O accumulators (their q index is g*4+i, sf lives at lane q)
    #pragma unroll
    for (int i = 0; i < 4; ++i) {
      float sfi = __shfl(sf, (g<<2) + i);
      #pragma unroll
      for (int nf = 0; nf < 8; ++nf) acc[nf][i] *= sfi;
    }

    // pack P to bf16 pairs and redistribute to A-fragment layout (q=lane&15, kv contiguous)
    u32 pk[4][2];
    #pragma unroll
    for (int mf = 0; mf < 4; ++mf) {
      pk[mf][0] = pack2bf(p[mf][0], p[mf][1]);
      pk[mf][1] = pack2bf(p[mf][2], p[mf][3]);
    }
    int srcA = qr + 32*(g & 1);
    int srcB = srcA + 16;
    bool hi = (g >> 1) & 1;
    #pragma unroll
    for (int ks = 0; ks < 2; ++ks) {
      u32 a0 = (u32)__shfl((int)pk[2*ks  ][0], srcA), a1 = (u32)__shfl((int)pk[2*ks  ][1], srcA);
      u32 b0 = (u32)__shfl((int)pk[2*ks+1][0], srcA), b1 = (u32)__shfl((int)pk[2*ks+1][1], srcA);
      u32 c0 = (u32)__shfl((int)pk[2*ks  ][0], srcB), c1 = (u32)__shfl((int)pk[2*ks  ][1], srcB);
      u32 d0 = (u32)__shfl((int)pk[2*ks+1][0], srcB), d1 = (u32)__shfl((int)pk[2*ks+1][1], srcB);
      uint4 pw;
      pw.x = hi ? b0 : a0;  pw.y = hi ? b1 : a1;
      pw.z = hi ? d0 : c0;  pw.w = hi ? d1 : c1;
      bf16x8 pa = __builtin_bit_cast(bf16x8, pw);
      #pragma unroll
      for (int nf = 0; nf < 8; ++nf) {
        int vr = nf*16 + qr;
        bf16x8 vf = *(const bf16x8*)(&Vs[vr*64 + ((g*8 + ks*32) ^ ((vr&7)<<3))]);
        acc[nf] = __builtin_amdgcn_mfma_f32_16x16x32_bf16(pa, vf, acc[nf], 0, 0, 0);
      }
    }
  }

  float linv[4];
  #pragma unroll
  for (int i = 0; i < 4; ++i) {
    float li = __shfl(l_run, (g<<2) + i);
    linv[i] = 1.0f / li;
  }
  #pragma unroll
  for (int nf = 0; nf < 8; ++nf)
    #pragma unroll
    for (int i = 0; i < 4; ++i) {
      int qrow = q0 + g*4 + i;
      Ob[((long)(b*S_ + qrow))*HID_ + h*HD_ + nf*16 + qr] = f2b(acc[nf][i] * linv[i]);
    }
}

extern "C" void kernel_launch(void* const* d_in, const int* in_sizes, int n_in,
                              void* d_out, int out_size, void* d_ws, size_t ws_size,
                              hipStream_t stream) {
  const float* hid = (const float*)d_in[0];
  const float* Wq  = (const float*)d_in[3];
  const float* bq  = (const float*)d_in[4];
  const float* Wk  = (const float*)d_in[5];
  const float* bk  = (const float*)d_in[6];
  const float* Wv  = (const float*)d_in[7];
  const float* bv  = (const float*)d_in[8];
  const float* Wo  = (const float*)d_in[9];
  char* ws = (char*)d_ws;
  float* cosT  = (float*)(ws + 0);
  float* sinT  = (float*)(ws + 524288);
  u16* hid_b   = (u16*)(ws + 1048576);
  u16* wqkv_b  = (u16*)(ws + 17825792);
  u16* wo_b    = (u16*)(ws + 28311552);
  float* Cqkv  = (float*)(ws + 36700160);
  u16* Qb      = (u16*)(ws + 78643200);
  u16* Kb      = (u16*)(ws + 95420416);
  u16* VTb     = (u16*)(ws + 97517568);
  u16* Ob      = (u16*)(ws + 99614720);

  hipLaunchKernelGGL(convert_kernel, dim3(17408), dim3(256), 0, stream,
                     hid, Wq, Wk, Wv, Wo, hid_b, wqkv_b, wo_b);
  hipLaunchKernelGGL(rope_kernel, dim3(512), dim3(256), 0, stream, cosT, sinT);
  hipLaunchKernelGGL(gemm_bt, dim3(32, 20), dim3(256), 0, stream,
                     hid_b, wqkv_b, Cqkv, NQKV_, KD_);
  hipLaunchKernelGGL(qkv_epilogue, dim3(2048, 2), dim3(256), 0, stream,
                     Cqkv, bq, bk, bv, cosT, sinT, Qb, Kb, VTb);
  hipLaunchKernelGGL(attn_kernel, dim3(32, 16, 2), dim3(256), 0, stream,
                     Qb, Kb, VTb, Ob);
  hipLaunchKernelGGL(gemm_bt, dim3(32, 16), dim3(256), 0, stream,
                     Ob, wo_b, (float*)d_out, HID_, KD_);
}

// Round 3
// 361.048 us; speedup vs baseline: 2.0944x; 1.4003x over previous
//
#include <hip/hip_runtime.h>

#define B_    2
#define S_    2048
#define HID_  2048
#define NH_   16
#define NKV_  2
#define HD_   128
#define M_    (B_*S_)     // 4096
#define NQKV_ 2560
#define KD_   2048

typedef unsigned short u16;
typedef unsigned int   u32;
typedef __bf16 bf16x8 __attribute__((ext_vector_type(8)));
typedef float  f32x4  __attribute__((ext_vector_type(4)));

#define GLOAD_LDS16(gp, lp) \
  __builtin_amdgcn_global_load_lds((const __attribute__((address_space(1))) unsigned int*)(gp), \
                                   (__attribute__((address_space(3))) unsigned int*)(lp), 16, 0, 0)

__device__ __forceinline__ u16 f2b(float x){
  u32 u = __builtin_bit_cast(u32, x);
  return (u16)((u + 0x7FFFu + ((u>>16)&1u)) >> 16);
}
__device__ __forceinline__ u32 pack2bf(float lo, float hi){
  u32 a = __builtin_bit_cast(u32, lo), b = __builtin_bit_cast(u32, hi);
  a = (a + 0x7FFFu + ((a>>16)&1u)) >> 16;
  b = (b + 0x7FFFu + ((b>>16)&1u)) >> 16;
  return a | (b<<16);
}

// ---------------- convert f32 -> bf16 (hidden, Wqkv concat, Wo) ----------------
__global__ void convert_kernel(const float* __restrict__ hid, const float* __restrict__ Wq,
                               const float* __restrict__ Wk, const float* __restrict__ Wv,
                               const float* __restrict__ Wo, u16* __restrict__ hid_b,
                               u16* __restrict__ wqkv_b, u16* __restrict__ wo_b) {
  long e = ((long)blockIdx.x*256 + threadIdx.x) * 4;
  const float* src; u16* dst; long off;
  if      (e <  8388608) { src = hid; dst = hid_b;            off = e; }
  else if (e < 12582912) { src = Wq;  dst = wqkv_b;           off = e -  8388608; }
  else if (e < 13107200) { src = Wk;  dst = wqkv_b + 4194304; off = e - 12582912; }
  else if (e < 13631488) { src = Wv;  dst = wqkv_b + 4718592; off = e - 13107200; }
  else                   { src = Wo;  dst = wo_b;             off = e - 13631488; }
  float4 v = *(const float4*)(src + off);
  u16 r0 = f2b(v.x), r1 = f2b(v.y), r2 = f2b(v.z), r3 = f2b(v.w);
  u32 lo = (u32)r0 | ((u32)r1<<16), hi2 = (u32)r2 | ((u32)r3<<16);
  *(uint2*)(dst + off) = make_uint2(lo, hi2);
}

// ---------------- RoPE tables [S][64] ----------------
__global__ void rope_kernel(float* __restrict__ cosT, float* __restrict__ sinT) {
  int idx = blockIdx.x*256 + threadIdx.x;   // S_*64
  int s = idx >> 6, d = idx & 63;
  float inv = powf(1000000.0f, -(float)d * (1.0f/64.0f));
  float ang = (float)s * inv;
  cosT[idx] = cosf(ang);
  sinT[idx] = sinf(ang);
}

// ---------------- bf16 B^T GEMM: C[m][n] = sum_k A[m][k]*Bw[n][k] ----------------
// m97 structure: tile 128x128, BK=32, 256 threads (4 waves 2x2),
// global_load_lds width=16 staging, linear LDS, 2 barriers per K-step.
__global__ __launch_bounds__(256) void gemm_bt(const u16* __restrict__ A, const u16* __restrict__ Bw,
                                               float* __restrict__ C, int Ndim, int Kdim) {
  __shared__ __align__(16) u16 As[128*32];
  __shared__ __align__(16) u16 Bs[128*32];
  int m0 = blockIdx.x*128, n0 = blockIdx.y*128;
  int tid = threadIdx.x, lane = tid & 63, w = tid >> 6;
  int wm = w & 1, wn = w >> 1;
  int r = lane & 15, g = lane >> 4;
  f32x4 acc[4][4] = {};

  const u16* aGP = A  + (long)(m0 + w*32 + (lane>>2))*Kdim + (lane&3)*8;
  const u16* bGP = Bw + (long)(n0 + w*32 + (lane>>2))*Kdim + (lane&3)*8;
  u16* aLP = As + w*1024;         // wave-uniform LDS base (u16 units; 2048B per wave)
  u16* bLP = Bs + w*1024;
  const long rowskip = (long)16*Kdim;

  for (int k0 = 0; k0 < Kdim; k0 += 32) {
    GLOAD_LDS16(aGP + k0,           aLP);
    GLOAD_LDS16(aGP + k0 + rowskip, aLP + 512);
    GLOAD_LDS16(bGP + k0,           bLP);
    GLOAD_LDS16(bGP + k0 + rowskip, bLP + 512);
    __syncthreads();
    bf16x8 af[4], bf[4];
    #pragma unroll
    for (int mf = 0; mf < 4; ++mf) af[mf] = *(const bf16x8*)(As + (wm*64 + mf*16 + r)*32 + g*8);
    #pragma unroll
    for (int nf = 0; nf < 4; ++nf) bf[nf] = *(const bf16x8*)(Bs + (wn*64 + nf*16 + r)*32 + g*8);
    #pragma unroll
    for (int mf = 0; mf < 4; ++mf)
      #pragma unroll
      for (int nf = 0; nf < 4; ++nf)
        acc[mf][nf] = __builtin_amdgcn_mfma_f32_16x16x32_bf16(af[mf], bf[nf], acc[mf][nf], 0, 0, 0);
    __syncthreads();
  }
  #pragma unroll
  for (int mf = 0; mf < 4; ++mf)
    #pragma unroll
    for (int nf = 0; nf < 4; ++nf)
      #pragma unroll
      for (int i = 0; i < 4; ++i) {
        int row = m0 + wm*64 + mf*16 + g*4 + i;
        int col = n0 + wn*64 + nf*16 + r;
        C[(long)row*Ndim + col] = acc[mf][nf][i];
      }
}

// ---------------- QKV epilogue: bias + RoPE + layout ----------------
__global__ void qkv_epilogue(const float* __restrict__ C, const float* __restrict__ bq,
                             const float* __restrict__ bk, const float* __restrict__ bv,
                             const float* __restrict__ cosT, const float* __restrict__ sinT,
                             u16* __restrict__ Qb, u16* __restrict__ Kb, u16* __restrict__ VTb) {
  int s = blockIdx.x, b = blockIdx.y, t = threadIdx.x;
  long m = (long)b*S_ + s;
  const float* Crow = C + m*NQKV_;
  const float* cr = cosT + s*64;
  const float* sr = sinT + s*64;
  // Q: 16 heads x 64 pairs = 1024 tasks
  #pragma unroll
  for (int it = 0; it < 4; ++it) {
    int task = t + it*256;
    int h = task >> 6, dp = task & 63;
    int c1 = h*128 + dp, c2 = c1 + 64;
    float x1 = Crow[c1] + bq[c1], x2 = Crow[c2] + bq[c2];
    float cc = cr[dp], ss = sr[dp];
    Qb[m*HID_ + c1] = f2b(x1*cc - x2*ss);
    Qb[m*HID_ + c2] = f2b(x2*cc + x1*ss);
  }
  // K: 2 heads x 64 pairs = 128 tasks
  if (t < 128) {
    int kvh = t >> 6, dp = t & 63;
    int c1 = kvh*128 + dp, c2 = c1 + 64;
    float x1 = Crow[2048 + c1] + bk[c1], x2 = Crow[2048 + c2] + bk[c2];
    float cc = cr[dp], ss = sr[dp];
    long base = ((long)(b*NKV_ + kvh)*S_ + s) * HD_;
    Kb[base + dp]      = f2b(x1*cc - x2*ss);
    Kb[base + dp + 64] = f2b(x2*cc + x1*ss);
  }
  // V: 256 tasks, store transposed [b][kvh][d][s]
  {
    int kvh = t >> 7, d = t & 127;
    float v = Crow[2304 + t] + bv[t];
    VTb[((long)(b*NKV_ + kvh)*HD_ + d)*S_ + s] = f2b(v);
  }
}

// ---------------- flash attention ----------------
// BQ=64 (4 waves x 16 rows), BK=64. Two qt-tiles per block (qt = 31-qtp, then qtp)
// for perfect causal balance: every block does exactly 33 tile-units.
// K/V double-buffered in LDS, staged via global_load_lds w=16 with the XOR
// swizzle applied to the GLOBAL source address (LDS dest stays linear).
// One barrier per tile; its implicit vmcnt-drain is the pipeline wait.
__device__ __forceinline__ void stage_tile(const u16* __restrict__ Kg, const u16* __restrict__ Vg,
                                           int kv0, u16* KsB, u16* VsB, int w, int lane) {
  #pragma unroll
  for (int j = 0; j < 4; ++j) {                       // K tile: [64][128] u16
    int row = w*16 + j*4 + (lane>>4);
    int col = ((lane&15)*8) ^ ((row&7)<<3);
    GLOAD_LDS16(Kg + (long)(kv0+row)*HD_ + col, KsB + (w*16 + j*4)*128);
  }
  #pragma unroll
  for (int j = 0; j < 4; ++j) {                       // VT tile: [128][64] u16
    int dd = w*32 + j*8 + (lane>>3);
    int col = ((lane&7)*8) ^ ((dd&7)<<3);
    GLOAD_LDS16(Vg + (long)dd*S_ + kv0 + col, VsB + (w*32 + j*8)*64);
  }
}

__global__ __launch_bounds__(256) void attn_kernel(const u16* __restrict__ Qb, const u16* __restrict__ Kb,
                                                   const u16* __restrict__ VTb, u16* __restrict__ Ob) {
  __shared__ __align__(16) u16 Ks[2][64*128];
  __shared__ __align__(16) u16 Vs[2][128*64];
  int qtp = blockIdx.x;                 // 0..15
  int h = blockIdx.y, b = blockIdx.z;
  int kvh = h >> 3;
  int tid = threadIdx.x, lane = tid & 63, w = tid >> 6;
  int qr = lane & 15, g = lane >> 4;

  const u16* Kg = Kb  + (long)(b*NKV_ + kvh)*S_*HD_;
  const u16* Vg = VTb + (long)(b*NKV_ + kvh)*HD_*S_;
  const float SCALE = 0.08838834764831845f;  // 1/sqrt(128)
  int cur = 0;

  #pragma unroll 1
  for (int half = 0; half < 2; ++half) {
    int qt = half ? qtp : (31 - qtp);
    int q0 = qt*64 + w*16;

    bf16x8 qf[4];
    const u16* qbase = Qb + ((long)(b*S_) + q0 + qr)*HID_ + h*HD_;
    #pragma unroll
    for (int kf = 0; kf < 4; ++kf) qf[kf] = *(const bf16x8*)(qbase + kf*32 + g*8);

    f32x4 acc[8] = {};
    float m_run = -3e38f, l_run = 0.f;
    int nt = qt + 1;

    stage_tile(Kg, Vg, 0, Ks[cur], Vs[cur], w, lane);
    __syncthreads();

    #pragma unroll 1
    for (int t = 0; t < nt; ++t) {
      int kv0 = t*64;
      if (t + 1 < nt)
        stage_tile(Kg, Vg, kv0 + 64, Ks[cur^1], Vs[cur^1], w, lane);

      const u16* KsC = Ks[cur];
      const u16* VsC = Vs[cur];

      // swapped QK^T: lane holds q=qr, kv = mf*16+g*4+i
      float p[4][4];
      #pragma unroll
      for (int mf = 0; mf < 4; ++mf) {
        f32x4 sacc = {};
        #pragma unroll
        for (int kf = 0; kf < 4; ++kf) {
          int kr = mf*16 + qr;
          bf16x8 kfr = *(const bf16x8*)(&KsC[kr*128 + ((g*8 + kf*32) ^ ((kr&7)<<3))]);
          sacc = __builtin_amdgcn_mfma_f32_16x16x32_bf16(kfr, qf[kf], sacc, 0, 0, 0);
        }
        #pragma unroll
        for (int i = 0; i < 4; ++i) p[mf][i] = sacc[i];
      }

      bool diag = (t == qt);
      float tmax = -3e38f;
      #pragma unroll
      for (int mf = 0; mf < 4; ++mf)
        #pragma unroll
        for (int i = 0; i < 4; ++i) {
          float sv = p[mf][i] * SCALE;
          if (diag) {
            int kvg = kv0 + mf*16 + g*4 + i;
            if (kvg > q0 + qr) sv = -1e9f;
          }
          p[mf][i] = sv;
          tmax = fmaxf(tmax, sv);
        }
      tmax = fmaxf(tmax, __shfl_xor(tmax, 16));
      tmax = fmaxf(tmax, __shfl_xor(tmax, 32));
      float m_new = fmaxf(m_run, tmax);
      float sf = __expf(m_run - m_new);
      float psum = 0.f;
      #pragma unroll
      for (int mf = 0; mf < 4; ++mf)
        #pragma unroll
        for (int i = 0; i < 4; ++i) {
          float ev = __expf(p[mf][i] - m_new);
          p[mf][i] = ev;
          psum += ev;
        }
      psum += __shfl_xor(psum, 16);
      psum += __shfl_xor(psum, 32);
      l_run = l_run * sf + psum;
      m_run = m_new;
      #pragma unroll
      for (int i = 0; i < 4; ++i) {
        float sfi = __shfl(sf, (g<<2) + i);
        #pragma unroll
        for (int nf = 0; nf < 8; ++nf) acc[nf][i] *= sfi;
      }

      // pack P to bf16 pairs, redistribute to A-fragment layout (q=lane&15)
      u32 pk[4][2];
      #pragma unroll
      for (int mf = 0; mf < 4; ++mf) {
        pk[mf][0] = pack2bf(p[mf][0], p[mf][1]);
        pk[mf][1] = pack2bf(p[mf][2], p[mf][3]);
      }
      int srcA = qr + 32*(g & 1);
      int srcB = srcA + 16;
      bool hi = (g >> 1) & 1;
      #pragma unroll
      for (int ks = 0; ks < 2; ++ks) {
        u32 a0 = (u32)__shfl((int)pk[2*ks  ][0], srcA), a1 = (u32)__shfl((int)pk[2*ks  ][1], srcA);
        u32 b0 = (u32)__shfl((int)pk[2*ks+1][0], srcA), b1 = (u32)__shfl((int)pk[2*ks+1][1], srcA);
        u32 c0 = (u32)__shfl((int)pk[2*ks  ][0], srcB), c1 = (u32)__shfl((int)pk[2*ks  ][1], srcB);
        u32 d0 = (u32)__shfl((int)pk[2*ks+1][0], srcB), d1 = (u32)__shfl((int)pk[2*ks+1][1], srcB);
        uint4 pw;
        pw.x = hi ? b0 : a0;  pw.y = hi ? b1 : a1;
        pw.z = hi ? d0 : c0;  pw.w = hi ? d1 : c1;
        bf16x8 pa = __builtin_bit_cast(bf16x8, pw);
        #pragma unroll
        for (int nf = 0; nf < 8; ++nf) {
          int vr = nf*16 + qr;
          bf16x8 vf = *(const bf16x8*)(&VsC[vr*64 + ((g*8 + ks*32) ^ ((vr&7)<<3))]);
          acc[nf] = __builtin_amdgcn_mfma_f32_16x16x32_bf16(pa, vf, acc[nf], 0, 0, 0);
        }
      }

      __syncthreads();   // implicit vmcnt drain completes next-tile staging
      cur ^= 1;
    }

    float linv[4];
    #pragma unroll
    for (int i = 0; i < 4; ++i) {
      float li = __shfl(l_run, (g<<2) + i);
      linv[i] = 1.0f / li;
    }
    #pragma unroll
    for (int nf = 0; nf < 8; ++nf)
      #pragma unroll
      for (int i = 0; i < 4; ++i) {
        int qrow = q0 + g*4 + i;
        Ob[((long)(b*S_ + qrow))*HID_ + h*HD_ + nf*16 + qr] = f2b(acc[nf][i] * linv[i]);
      }
  }
}

extern "C" void kernel_launch(void* const* d_in, const int* in_sizes, int n_in,
                              void* d_out, int out_size, void* d_ws, size_t ws_size,
                              hipStream_t stream) {
  const float* hid = (const float*)d_in[0];
  const float* Wq  = (const float*)d_in[3];
  const float* bq  = (const float*)d_in[4];
  const float* Wk  = (const float*)d_in[5];
  const float* bk  = (const float*)d_in[6];
  const float* Wv  = (const float*)d_in[7];
  const float* bv  = (const float*)d_in[8];
  const float* Wo  = (const float*)d_in[9];
  char* ws = (char*)d_ws;
  float* cosT  = (float*)(ws + 0);
  float* sinT  = (float*)(ws + 524288);
  u16* hid_b   = (u16*)(ws + 1048576);
  u16* wqkv_b  = (u16*)(ws + 17825792);
  u16* wo_b    = (u16*)(ws + 28311552);
  float* Cqkv  = (float*)(ws + 36700160);
  u16* Qb      = (u16*)(ws + 78643200);
  u16* Kb      = (u16*)(ws + 95420416);
  u16* VTb     = (u16*)(ws + 97517568);
  u16* Ob      = (u16*)(ws + 99614720);

  hipLaunchKernelGGL(convert_kernel, dim3(17408), dim3(256), 0, stream,
                     hid, Wq, Wk, Wv, Wo, hid_b, wqkv_b, wo_b);
  hipLaunchKernelGGL(rope_kernel, dim3(512), dim3(256), 0, stream, cosT, sinT);
  hipLaunchKernelGGL(gemm_bt, dim3(32, 20), dim3(256), 0, stream,
                     hid_b, wqkv_b, Cqkv, NQKV_, KD_);
  hipLaunchKernelGGL(qkv_epilogue, dim3(2048, 2), dim3(256), 0, stream,
                     Cqkv, bq, bk, bv, cosT, sinT, Qb, Kb, VTb);
  hipLaunchKernelGGL(attn_kernel, dim3(16, 16, 2), dim3(256), 0, stream,
                     Qb, Kb, VTb, Ob);
  hipLaunchKernelGGL(gemm_bt, dim3(32, 16), dim3(256), 0, stream,
                     Ob, wo_b, (float*)d_out, HID_, KD_);
}

// Round 5
// 347.313 us; speedup vs baseline: 2.1772x; 1.0395x over previous
//
#include <hip/hip_runtime.h>

#define B_    2
#define S_    2048
#define HID_  2048
#define NH_   16
#define NKV_  2
#define HD_   128
#define M_    (B_*S_)     // 4096
#define NQKV_ 2560
#define KD_   2048

typedef unsigned short u16;
typedef unsigned int   u32;
typedef __bf16 bf16x8 __attribute__((ext_vector_type(8)));
typedef float  f32x4  __attribute__((ext_vector_type(4)));

#define GLOAD_LDS16(gp, lp) \
  __builtin_amdgcn_global_load_lds((const __attribute__((address_space(1))) unsigned int*)(gp), \
                                   (__attribute__((address_space(3))) unsigned int*)(lp), 16, 0, 0)

__device__ __forceinline__ u16 f2b(float x){
  u32 u = __builtin_bit_cast(u32, x);
  return (u16)((u + 0x7FFFu + ((u>>16)&1u)) >> 16);
}
__device__ __forceinline__ u32 pack2bf(float lo, float hi){
  u32 a = __builtin_bit_cast(u32, lo), b = __builtin_bit_cast(u32, hi);
  a = (a + 0x7FFFu + ((a>>16)&1u)) >> 16;
  b = (b + 0x7FFFu + ((b>>16)&1u)) >> 16;
  return a | (b<<16);
}

// ---------------- convert f32 -> bf16 (hidden, Wqkv concat, Wo) ----------------
__global__ void convert_kernel(const float* __restrict__ hid, const float* __restrict__ Wq,
                               const float* __restrict__ Wk, const float* __restrict__ Wv,
                               const float* __restrict__ Wo, u16* __restrict__ hid_b,
                               u16* __restrict__ wqkv_b, u16* __restrict__ wo_b) {
  long e = ((long)blockIdx.x*256 + threadIdx.x) * 4;
  const float* src; u16* dst; long off;
  if      (e <  8388608) { src = hid; dst = hid_b;            off = e; }
  else if (e < 12582912) { src = Wq;  dst = wqkv_b;           off = e -  8388608; }
  else if (e < 13107200) { src = Wk;  dst = wqkv_b + 4194304; off = e - 12582912; }
  else if (e < 13631488) { src = Wv;  dst = wqkv_b + 4718592; off = e - 13107200; }
  else                   { src = Wo;  dst = wo_b;             off = e - 13631488; }
  float4 v = *(const float4*)(src + off);
  u16 r0 = f2b(v.x), r1 = f2b(v.y), r2 = f2b(v.z), r3 = f2b(v.w);
  u32 lo = (u32)r0 | ((u32)r1<<16), hi2 = (u32)r2 | ((u32)r3<<16);
  *(uint2*)(dst + off) = make_uint2(lo, hi2);
}

// ---------------- RoPE tables [S][64] ----------------
__global__ void rope_kernel(float* __restrict__ cosT, float* __restrict__ sinT) {
  int idx = blockIdx.x*256 + threadIdx.x;   // S_*64
  int s = idx >> 6, d = idx & 63;
  float inv = powf(1000000.0f, -(float)d * (1.0f/64.0f));
  float ang = (float)s * inv;
  cosT[idx] = cosf(ang);
  sinT[idx] = sinf(ang);
}

// ---------------- bf16 B^T GEMM: C[m][n] = sum_k A[m][k]*Bw[n][k] ----------------
// 128x128 tile, BK=32, 4 waves (2x2), global_load_lds w=16, DOUBLE-BUFFERED:
// stage K-step t+1 into buf^1, compute buf, ONE barrier per K-step (its
// implicit vmcnt drain completes the t+1 staging).
__global__ __launch_bounds__(256) void gemm_bt(const u16* __restrict__ A, const u16* __restrict__ Bw,
                                               float* __restrict__ C, int Ndim, int Kdim) {
  __shared__ __align__(16) u16 As[2][128*32];
  __shared__ __align__(16) u16 Bs[2][128*32];
  int m0 = blockIdx.x*128, n0 = blockIdx.y*128;
  int tid = threadIdx.x, lane = tid & 63, w = tid >> 6;
  int wm = w & 1, wn = w >> 1;
  int r = lane & 15, g = lane >> 4;
  f32x4 acc[4][4] = {};

  // lane l's 16B lands at wave_base + j*1024 + l*16 -> row=w*32+j*16+(l>>2), col=(l&3)*8
  const u16* aGP = A  + (long)(m0 + w*32 + (lane>>2))*Kdim + (lane&3)*8;
  const u16* bGP = Bw + (long)(n0 + w*32 + (lane>>2))*Kdim + (lane&3)*8;
  const long rowskip = (long)16*Kdim;

  // prologue: stage k0=0 into buffer 0
  GLOAD_LDS16(aGP,           As[0] + w*1024);
  GLOAD_LDS16(aGP + rowskip, As[0] + w*1024 + 512);
  GLOAD_LDS16(bGP,           Bs[0] + w*1024);
  GLOAD_LDS16(bGP + rowskip, Bs[0] + w*1024 + 512);
  __syncthreads();

  int cur = 0;
  for (int k0 = 0; k0 < Kdim; k0 += 32) {
    if (k0 + 32 < Kdim) {
      int kn = k0 + 32;
      GLOAD_LDS16(aGP + kn,           As[cur^1] + w*1024);
      GLOAD_LDS16(aGP + kn + rowskip, As[cur^1] + w*1024 + 512);
      GLOAD_LDS16(bGP + kn,           Bs[cur^1] + w*1024);
      GLOAD_LDS16(bGP + kn + rowskip, Bs[cur^1] + w*1024 + 512);
    }
    const u16* Ac = As[cur];
    const u16* Bc = Bs[cur];
    bf16x8 af[4], bf[4];
    #pragma unroll
    for (int mf = 0; mf < 4; ++mf) af[mf] = *(const bf16x8*)(Ac + (wm*64 + mf*16 + r)*32 + g*8);
    #pragma unroll
    for (int nf = 0; nf < 4; ++nf) bf[nf] = *(const bf16x8*)(Bc + (wn*64 + nf*16 + r)*32 + g*8);
    #pragma unroll
    for (int mf = 0; mf < 4; ++mf)
      #pragma unroll
      for (int nf = 0; nf < 4; ++nf)
        acc[mf][nf] = __builtin_amdgcn_mfma_f32_16x16x32_bf16(af[mf], bf[nf], acc[mf][nf], 0, 0, 0);
    __syncthreads();   // drains vmcnt: next buffer ready; cur safe to overwrite next iter
    cur ^= 1;
  }
  #pragma unroll
  for (int mf = 0; mf < 4; ++mf)
    #pragma unroll
    for (int nf = 0; nf < 4; ++nf)
      #pragma unroll
      for (int i = 0; i < 4; ++i) {
        int row = m0 + wm*64 + mf*16 + g*4 + i;
        int col = n0 + wn*64 + nf*16 + r;
        C[(long)row*Ndim + col] = acc[mf][nf][i];
      }
}

// ---------------- QKV epilogue: bias + RoPE + layout ----------------
__global__ void qkv_epilogue(const float* __restrict__ C, const float* __restrict__ bq,
                             const float* __restrict__ bk, const float* __restrict__ bv,
                             const float* __restrict__ cosT, const float* __restrict__ sinT,
                             u16* __restrict__ Qb, u16* __restrict__ Kb, u16* __restrict__ VTb) {
  int s = blockIdx.x, b = blockIdx.y, t = threadIdx.x;
  long m = (long)b*S_ + s;
  const float* Crow = C + m*NQKV_;
  const float* cr = cosT + s*64;
  const float* sr = sinT + s*64;
  #pragma unroll
  for (int it = 0; it < 4; ++it) {
    int task = t + it*256;
    int h = task >> 6, dp = task & 63;
    int c1 = h*128 + dp, c2 = c1 + 64;
    float x1 = Crow[c1] + bq[c1], x2 = Crow[c2] + bq[c2];
    float cc = cr[dp], ss = sr[dp];
    Qb[m*HID_ + c1] = f2b(x1*cc - x2*ss);
    Qb[m*HID_ + c2] = f2b(x2*cc + x1*ss);
  }
  if (t < 128) {
    int kvh = t >> 6, dp = t & 63;
    int c1 = kvh*128 + dp, c2 = c1 + 64;
    float x1 = Crow[2048 + c1] + bk[c1], x2 = Crow[2048 + c2] + bk[c2];
    float cc = cr[dp], ss = sr[dp];
    long base = ((long)(b*NKV_ + kvh)*S_ + s) * HD_;
    Kb[base + dp]      = f2b(x1*cc - x2*ss);
    Kb[base + dp + 64] = f2b(x2*cc + x1*ss);
  }
  {
    int kvh = t >> 7, d = t & 127;
    float v = Crow[2304 + t] + bv[t];
    VTb[((long)(b*NKV_ + kvh)*HD_ + d)*S_ + s] = f2b(v);
  }
}

// ---------------- flash attention ----------------
// BQ=64 (4 waves x 16 rows), BK=64, qt-paired for causal balance, dbuf LDS via
// global_load_lds with source-side XOR swizzle. This round: log2-domain
// softmax (exp2 direct), defer-max rescale (T13), setprio around MFMA (T5),
// hoisted pre-swizzled stage pointers.
__device__ __forceinline__ void stage_tile(const u16* kpe, const u16* kpo, const u16* vp,
                                           u16* KsB, u16* VsB, int w) {
  GLOAD_LDS16(kpe,            KsB + (w*16     )*128);
  GLOAD_LDS16(kpo + 4*HD_,    KsB + (w*16 +  4)*128);
  GLOAD_LDS16(kpe + 8*HD_,    KsB + (w*16 +  8)*128);
  GLOAD_LDS16(kpo + 12*HD_,   KsB + (w*16 + 12)*128);
  #pragma unroll
  for (int j = 0; j < 4; ++j)
    GLOAD_LDS16(vp + (long)j*8*S_, VsB + (w*32 + j*8)*64);
}

__global__ __launch_bounds__(256) void attn_kernel(const u16* __restrict__ Qb, const u16* __restrict__ Kb,
                                                   const u16* __restrict__ VTb, u16* __restrict__ Ob) {
  __shared__ __align__(16) u16 Ks[2][64*128];
  __shared__ __align__(16) u16 Vs[2][128*64];
  int qtp = blockIdx.x;                 // 0..15
  int h = blockIdx.y, b = blockIdx.z;
  int kvh = h >> 3;
  int tid = threadIdx.x, lane = tid & 63, w = tid >> 6;
  int qr = lane & 15, g = lane >> 4;

  const u16* Kg = Kb  + (long)(b*NKV_ + kvh)*S_*HD_;
  const u16* Vg = VTb + (long)(b*NKV_ + kvh)*HD_*S_;
  // per-lane pre-swizzled staging bases (tile kv0=0); advance per tile
  const u16* kpe0 = Kg + (long)(w*16 + (lane>>4))*HD_ + (((lane&15)*8) ^ ((lane>>4)<<3));
  const u16* kpo0 = Kg + (long)(w*16 + (lane>>4))*HD_ + (((lane&15)*8) ^ ((lane>>4)<<3) ^ 32);
  const u16* vp0  = Vg + (long)(w*32 + (lane>>3))*S_  + (((lane&7)*8)  ^ ((lane>>3)<<3));

  const float SCALE2 = 0.1275437939911537f;  // (1/sqrt(128)) * log2(e)
  const float THR = 11.5f;                   // defer-max threshold (log2 domain)
  int cur = 0;

  #pragma unroll 1
  for (int half = 0; half < 2; ++half) {
    int qt = half ? qtp : (31 - qtp);
    int q0 = qt*64 + w*16;

    bf16x8 qf[4];
    const u16* qbase = Qb + ((long)(b*S_) + q0 + qr)*HID_ + h*HD_;
    #pragma unroll
    for (int kf = 0; kf < 4; ++kf) qf[kf] = *(const bf16x8*)(qbase + kf*32 + g*8);

    f32x4 acc[8] = {};
    float m_run = -3e38f, l_run = 0.f;
    int nt = qt + 1;

    const u16* kpe = kpe0; const u16* kpo = kpo0; const u16* vp = vp0;
    stage_tile(kpe, kpo, vp, Ks[cur], Vs[cur], w);
    __syncthreads();

    #pragma unroll 1
    for (int t = 0; t < nt; ++t) {
      int kv0 = t*64;
      if (t + 1 < nt) {
        kpe += 64*HD_; kpo += 64*HD_; vp += 64;
        stage_tile(kpe, kpo, vp, Ks[cur^1], Vs[cur^1], w);
      }
      const u16* KsC = Ks[cur];
      const u16* VsC = Vs[cur];

      // swapped QK^T: lane holds q=qr, kv = mf*16+g*4+i
      float p[4][4];
      __builtin_amdgcn_s_setprio(1);
      #pragma unroll
      for (int mf = 0; mf < 4; ++mf) {
        f32x4 sacc = {};
        #pragma unroll
        for (int kf = 0; kf < 4; ++kf) {
          int kr = mf*16 + qr;
          bf16x8 kfr = *(const bf16x8*)(&KsC[kr*128 + ((g*8 + kf*32) ^ ((kr&7)<<3))]);
          sacc = __builtin_amdgcn_mfma_f32_16x16x32_bf16(kfr, qf[kf], sacc, 0, 0, 0);
        }
        #pragma unroll
        for (int i = 0; i < 4; ++i) p[mf][i] = sacc[i];
      }
      __builtin_amdgcn_s_setprio(0);

      bool diag = (t == qt);
      float tmax = -3e38f;
      #pragma unroll
      for (int mf = 0; mf < 4; ++mf)
        #pragma unroll
        for (int i = 0; i < 4; ++i) {
          float sv = p[mf][i] * SCALE2;          // log2 domain
          if (diag) {
            int kvg = kv0 + mf*16 + g*4 + i;
            if (kvg > q0 + qr) sv = -1e9f;
          }
          p[mf][i] = sv;
          tmax = fmaxf(tmax, sv);
        }
      tmax = fmaxf(tmax, __shfl_xor(tmax, 16));
      tmax = fmaxf(tmax, __shfl_xor(tmax, 32));

      if (!__all(tmax - m_run <= THR)) {       // defer-max: rescale only on real growth
        float m_new = fmaxf(m_run, tmax);
        float sf = exp2f(m_run - m_new);
        #pragma unroll
        for (int i = 0; i < 4; ++i) {
          float sfi = __shfl(sf, (g<<2) + i);
          #pragma unroll
          for (int nf = 0; nf < 8; ++nf) acc[nf][i] *= sfi;
        }
        l_run *= sf;
        m_run = m_new;
      }
      float psum = 0.f;
      #pragma unroll
      for (int mf = 0; mf < 4; ++mf)
        #pragma unroll
        for (int i = 0; i < 4; ++i) {
          float ev = exp2f(p[mf][i] - m_run);  // bounded by 2^THR
          p[mf][i] = ev;
          psum += ev;
        }
      psum += __shfl_xor(psum, 16);
      psum += __shfl_xor(psum, 32);
      l_run += psum;

      // pack P to bf16 pairs, redistribute to A-fragment layout (q=lane&15)
      u32 pk[4][2];
      #pragma unroll
      for (int mf = 0; mf < 4; ++mf) {
        pk[mf][0] = pack2bf(p[mf][0], p[mf][1]);
        pk[mf][1] = pack2bf(p[mf][2], p[mf][3]);
      }
      int srcA = qr + 32*(g & 1);
      int srcB = srcA + 16;
      bool hi = (g >> 1) & 1;
      #pragma unroll
      for (int ks = 0; ks < 2; ++ks) {
        u32 a0 = (u32)__shfl((int)pk[2*ks  ][0], srcA), a1 = (u32)__shfl((int)pk[2*ks  ][1], srcA);
        u32 b0 = (u32)__shfl((int)pk[2*ks+1][0], srcA), b1 = (u32)__shfl((int)pk[2*ks+1][1], srcA);
        u32 c0 = (u32)__shfl((int)pk[2*ks  ][0], srcB), c1 = (u32)__shfl((int)pk[2*ks  ][1], srcB);
        u32 d0 = (u32)__shfl((int)pk[2*ks+1][0], srcB), d1 = (u32)__shfl((int)pk[2*ks+1][1], srcB);
        uint4 pw;
        pw.x = hi ? b0 : a0;  pw.y = hi ? b1 : a1;
        pw.z = hi ? d0 : c0;  pw.w = hi ? d1 : c1;
        bf16x8 pa = __builtin_bit_cast(bf16x8, pw);
        __builtin_amdgcn_s_setprio(1);
        #pragma unroll
        for (int nf = 0; nf < 8; ++nf) {
          int vr = nf*16 + qr;
          bf16x8 vf = *(const bf16x8*)(&VsC[vr*64 + ((g*8 + ks*32) ^ ((vr&7)<<3))]);
          acc[nf] = __builtin_amdgcn_mfma_f32_16x16x32_bf16(pa, vf, acc[nf], 0, 0, 0);
        }
        __builtin_amdgcn_s_setprio(0);
      }

      __syncthreads();   // implicit vmcnt drain completes next-tile staging
      cur ^= 1;
    }

    float linv[4];
    #pragma unroll
    for (int i = 0; i < 4; ++i) {
      float li = __shfl(l_run, (g<<2) + i);
      linv[i] = 1.0f / li;
    }
    #pragma unroll
    for (int nf = 0; nf < 8; ++nf)
      #pragma unroll
      for (int i = 0; i < 4; ++i) {
        int qrow = q0 + g*4 + i;
        Ob[((long)(b*S_ + qrow))*HID_ + h*HD_ + nf*16 + qr] = f2b(acc[nf][i] * linv[i]);
      }
  }
}

extern "C" void kernel_launch(void* const* d_in, const int* in_sizes, int n_in,
                              void* d_out, int out_size, void* d_ws, size_t ws_size,
                              hipStream_t stream) {
  const float* hid = (const float*)d_in[0];
  const float* Wq  = (const float*)d_in[3];
  const float* bq  = (const float*)d_in[4];
  const float* Wk  = (const float*)d_in[5];
  const float* bk  = (const float*)d_in[6];
  const float* Wv  = (const float*)d_in[7];
  const float* bv  = (const float*)d_in[8];
  const float* Wo  = (const float*)d_in[9];
  char* ws = (char*)d_ws;
  float* cosT  = (float*)(ws + 0);
  float* sinT  = (float*)(ws + 524288);
  u16* hid_b   = (u16*)(ws + 1048576);
  u16* wqkv_b  = (u16*)(ws + 17825792);
  u16* wo_b    = (u16*)(ws + 28311552);
  float* Cqkv  = (float*)(ws + 36700160);
  u16* Qb      = (u16*)(ws + 78643200);
  u16* Kb      = (u16*)(ws + 95420416);
  u16* VTb     = (u16*)(ws + 97517568);
  u16* Ob      = (u16*)(ws + 99614720);

  hipLaunchKernelGGL(convert_kernel, dim3(17408), dim3(256), 0, stream,
                     hid, Wq, Wk, Wv, Wo, hid_b, wqkv_b, wo_b);
  hipLaunchKernelGGL(rope_kernel, dim3(512), dim3(256), 0, stream, cosT, sinT);
  hipLaunchKernelGGL(gemm_bt, dim3(32, 20), dim3(256), 0, stream,
                     hid_b, wqkv_b, Cqkv, NQKV_, KD_);
  hipLaunchKernelGGL(qkv_epilogue, dim3(2048, 2), dim3(256), 0, stream,
                     Cqkv, bq, bk, bv, cosT, sinT, Qb, Kb, VTb);
  hipLaunchKernelGGL(attn_kernel, dim3(16, 16, 2), dim3(256), 0, stream,
                     Qb, Kb, VTb, Ob);
  hipLaunchKernelGGL(gemm_bt, dim3(32, 16), dim3(256), 0, stream,
                     Ob, wo_b, (float*)d_out, HID_, KD_);
}